// Round 2
// baseline (159.177 us; speedup 1.0000x reference)
//
#include <hip/hip_runtime.h>
#include <hip/hip_bf16.h>

#define EMB   1024
#define HS    64
#define BATCH 4
#define SEQ   4096
#define MTOT  (BATCH*SEQ)   // 16384

#define WAIT_LGKM0() asm volatile("s_waitcnt lgkmcnt(0)" ::: "memory")

typedef float  f32x4 __attribute__((ext_vector_type(4)));
typedef short  s16x8 __attribute__((ext_vector_type(8)));
typedef __bf16 bf16x8 __attribute__((ext_vector_type(8)));

__device__ __forceinline__ unsigned short f2bf(float f) {
    unsigned int u = __float_as_uint(f);
    u = (u + 0x7fffu + ((u >> 16) & 1u)) >> 16;   // RNE
    return (unsigned short)u;
}
__device__ __forceinline__ unsigned int pkbf(float lo, float hi) {
#if __has_builtin(__builtin_amdgcn_cvt_pk_bf16_f32)
    return __builtin_bit_cast(unsigned int,
        __builtin_amdgcn_cvt_pk_bf16_f32(lo, hi));
#else
    return (unsigned int)f2bf(lo) | ((unsigned int)f2bf(hi) << 16);
#endif
}
__device__ __forceinline__ s16x8 cvt8(float4 a, float4 b) {
    union { unsigned int u[4]; s16x8 v; } r;
    r.u[0] = pkbf(a.x, a.y); r.u[1] = pkbf(a.z, a.w);
    r.u[2] = pkbf(b.x, b.y); r.u[3] = pkbf(b.z, b.w);
    return r.v;
}
__device__ __forceinline__ f32x4 mfma16(s16x8 a, s16x8 b, f32x4 c) {
    return __builtin_amdgcn_mfma_f32_16x16x32_bf16(
        __builtin_bit_cast(bf16x8, a), __builtin_bit_cast(bf16x8, b), c, 0, 0, 0);
}
// async global->LDS, 16B/lane; lds dest = uniform base + lane*16
__device__ __forceinline__ void ld_lds16(const void* g, unsigned short* l) {
    __builtin_amdgcn_global_load_lds(
        (const __attribute__((address_space(1))) unsigned int*)g,
        (__attribute__((address_space(3))) unsigned int*)l, 16, 0, 0);
}

// ---------------------------------------------------------------------------
// Kernel 1: pack W (fp32 [1024,64] x3) into MFMA-B-fragment order, bf16.
// t 0-3 -> Wq (pre-scaled by 1/32 == emb^-0.5, exact), 4-7 -> Wk, 8-11 -> Wv
// ---------------------------------------------------------------------------
__global__ __launch_bounds__(256) void pack_w(const float* __restrict__ Wq,
                                              const float* __restrict__ Wk,
                                              const float* __restrict__ Wv,
                                              unsigned short* __restrict__ wp) {
    int idx = blockIdx.x * 256 + threadIdx.x;     // 0 .. 24575
    int l = idx & 63;
    int s = (idx >> 6) & 31;
    int t = idx >> 11;                            // 0..11
    const float* W = (t < 4) ? Wq : (t < 8) ? Wk : Wv;
    float scale = (t < 4) ? 0.03125f : 1.0f;
    int n  = ((t & 3) * 16) + (l & 15);
    int k0 = s * 32 + ((l >> 4) * 8);
    s16x8 v;
#pragma unroll
    for (int j = 0; j < 8; j++)
        v[j] = (short)f2bf(W[(size_t)(k0 + j) * HS + n] * scale);
    *(s16x8*)(wp + (size_t)idx * 8) = v;
}

// ---------------------------------------------------------------------------
// Kernel 2 (R8 proven): fused QKV projection, BK=64 double-steps.
// Block = 32 rows x 192 cols, 512 blocks (2/CU).
// ---------------------------------------------------------------------------
__global__ __launch_bounds__(256) void proj(const float* __restrict__ x,
                                            const unsigned short* __restrict__ wp,
                                            unsigned short* __restrict__ qws,
                                            unsigned short* __restrict__ kws,
                                            unsigned short* __restrict__ vtws) {
    __shared__ unsigned short xb[2][2][2048];     // [buf][sub] 4 KB each
    __shared__ unsigned short wb2[2][12288];      // [buf] 24 KB each
    __shared__ unsigned short vt[32][72];         // V transpose staging
    int l = threadIdx.x & 63, w = threadIdx.x >> 6;
    int lane15 = l & 15, quad = l >> 4;
    int rh = w & 1, ts = w >> 1;
    int row0 = blockIdx.x * 32;

    auto stage = [&](int buf, int sg2) {
        int d = w * 64 + l;
        int row = d >> 3, cs = d & 7;
        int sc = cs ^ (row & 7);                  // XOR swizzle (bank spread)
#pragma unroll
        for (int sp = 0; sp < 2; sp++)
            ld_lds16(x + (size_t)(row0 + row) * EMB + sg2 * 64 + sp * 32 + sc * 4,
                     &xb[buf][sp][w * 512]);
#pragma unroll
        for (int j = 0; j < 6; j++) {
            int f = w + 4 * j;
            int sp = f / 12, t = f % 12;
            ld_lds16(wp + ((size_t)(t * 32 + sg2 * 2 + sp) * 64 + l) * 8,
                     &wb2[buf][f * 512]);
        }
    };

    int xrow = rh * 16 + lane15;
    int rsw = xrow & 7;
    f32x4 acc[6] = {};

    stage(0, 0);
    int buf = 0;
    for (int sg2 = 0; sg2 < 16; sg2++) {
        __syncthreads();
        if (sg2 < 15) stage(buf ^ 1, sg2 + 1);
#pragma unroll
        for (int sp = 0; sp < 2; sp++) {
            float4 lo = *(const float4*)&xb[buf][sp][(xrow * 8 + ((2 * quad)     ^ rsw)) * 8];
            float4 hi = *(const float4*)&xb[buf][sp][(xrow * 8 + ((2 * quad + 1) ^ rsw)) * 8];
            s16x8 af = cvt8(lo, hi);
#pragma unroll
            for (int j = 0; j < 6; j++) {
                int t = ts + 2 * j;
                s16x8 bfr = *(const s16x8*)&wb2[buf][(sp * 12 + t) * 512 + l * 8];
                acc[j] = mfma16(af, bfr, acc[j]);
            }
        }
        buf ^= 1;
    }

#pragma unroll
    for (int r = 0; r < 4; r++) {
        int row = row0 + rh * 16 + quad * 4 + r;
#pragma unroll
        for (int j = 0; j < 2; j++) {
            int tq = ts + 2 * j;
            qws[(size_t)row * HS + tq * 16 + lane15] = f2bf(acc[j][r]);
            kws[(size_t)row * HS + tq * 16 + lane15] = f2bf(acc[j + 2][r]);
            vt[rh * 16 + quad * 4 + r][tq * 16 + lane15] = f2bf(acc[j + 4][r]);
        }
    }
    __syncthreads();
    if (threadIdx.x < 128) {
        int h = threadIdx.x & 63, half = threadIdx.x >> 6;
        int b = row0 >> 12, tp0 = row0 & (SEQ - 1);
        unsigned short tmp[16];
#pragma unroll
        for (int j = 0; j < 16; j++) tmp[j] = vt[half * 16 + j][h];
        unsigned short* dst = vtws + ((size_t)b * HS + h) * SEQ + tp0 + half * 16;
        *(s16x8*)dst       = *(s16x8*)tmp;
        *(s16x8*)(dst + 8) = *(s16x8*)(tmp + 8);
    }
}

// ---------------------------------------------------------------------------
// Kernel 3: flash attention, 128-row q-block (2 16-row frags / wave),
// chunk = 16 k-tiles, 320 blocks (single resident round at 2/CU).
// Sync: barrier DOUBLE-BUFFER (m97 pattern) — producer wave (w==4) issues
// global_load_lds for tile s+1; its __syncthreads arrival carries the
// implicit vmcnt(0) drain, consumers' arrival drains their lgkm reads.
// Provably correct: no hand-rolled ready/done tokens (R1's ring raced).
// ---------------------------------------------------------------------------
__global__ __launch_bounds__(320) void attn_part(const unsigned short* __restrict__ qws,
                                                 const unsigned short* __restrict__ kws,
                                                 const unsigned short* __restrict__ vtws,
                                                 float* __restrict__ op,
                                                 float* __restrict__ lp) {
    __shared__ unsigned short ldsKV[2][2][4096];  // [buf][K|V] 8 KB each = 32 KB
    __shared__ unsigned short plds[4][2][16][72]; // [wave][frag] 18 KB

    int l = threadIdx.x & 63;
    int w = threadIdx.x >> 6;                     // 0..4
    int lane15 = l & 15, quad = l >> 4;

    int W = blockIdx.x;                           // 0..319
    int b = W / 80;
    int g = W - b * 80;
    int a = 0;
    while (g >= 4 * (a + 1) * (a + 2)) a++;       // a in [0,3]
    int off = g - 4 * a * (a + 1);
    int oQ  = off / (a + 1);
    int c   = off - oQ * (a + 1);
    int Q   = 8 * a + oQ;                         // 128-row q-block, 0..31
    int lenT = 2 * (Q + 1);                       // k-tiles covered by q-block
    int t0 = c * 16;
    int steps = min(16, lenT - t0);               // 2..16, uniform in block
    int diagT = 2 * Q;                            // tiles >= diagT need masking

    auto stage = [&](int buf, int kt) {
        int c0 = kt * 64;
#pragma unroll
        for (int s2 = 0; s2 < 8; s2++) {          // K slots
            int t = s2 >> 1, h = s2 & 1;
            ld_lds16(kws + ((size_t)b * SEQ + c0 + t * 16 + lane15) * HS
                         + h * 32 + quad * 8,
                     &ldsKV[buf][0][s2 * 512]);
        }
#pragma unroll
        for (int s2 = 0; s2 < 8; s2++) {          // V slots
            int t = s2 >> 1, h = s2 & 1;
            ld_lds16(vtws + ((size_t)b * HS + t * 16 + lane15) * SEQ
                          + c0 + h * 32 + quad * 8,
                     &ldsKV[buf][1][s2 * 512]);
        }
    };

    int q0 = Q * 128 + (w & 3) * 32;              // consumer's first q-row
    s16x8 qf00 = {}, qf01 = {}, qf10 = {}, qf11 = {};
    f32x4 o0[4] = {}, o1[4] = {};
    float ls0[4] = {0.f, 0.f, 0.f, 0.f};
    float ls1[4] = {0.f, 0.f, 0.f, 0.f};

    if (w == 4) {
        stage(0, t0);                             // prologue: tile 0 -> buf 0
    } else {
        const unsigned short* qb0 =
            qws + ((size_t)b * SEQ + q0 + lane15) * HS + quad * 8;
        const unsigned short* qb1 = qb0 + 16 * HS;
        qf00 = *(const s16x8*)(qb0);
        qf01 = *(const s16x8*)(qb0 + 32);
        qf10 = *(const s16x8*)(qb1);
        qf11 = *(const s16x8*)(qb1 + 32);
    }

    int buf = 0;
    for (int s = 0; s < steps; s++) {
        __syncthreads();                          // tile s landed; buf^1 free
        if (w == 4) {
            if (s + 1 < steps) stage(buf ^ 1, t0 + s + 1);
        } else {
            int kt = t0 + s;
            const unsigned short* Kb = ldsKV[buf][0];
            const unsigned short* Vb = ldsKV[buf][1];

            f32x4 s0[4] = {}, s1[4] = {};
#pragma unroll
            for (int t = 0; t < 4; t++) {
                s16x8 kf0 = *(const s16x8*)(Kb + (2 * t) * 512 + l * 8);
                s16x8 kf1 = *(const s16x8*)(Kb + (2 * t + 1) * 512 + l * 8);
                s0[t] = mfma16(qf00, kf0, s0[t]);
                s0[t] = mfma16(qf01, kf1, s0[t]);
                s1[t] = mfma16(qf10, kf0, s1[t]);
                s1[t] = mfma16(qf11, kf1, s1[t]);
            }
            if (kt >= diagT) {
                int c0 = kt * 64;
#pragma unroll
                for (int t = 0; t < 4; t++)
#pragma unroll
                    for (int r = 0; r < 4; r++) {
                        int kcol = c0 + t * 16 + lane15;
                        if (kcol > q0 + quad * 4 + r)      s0[t][r] = -1e30f;
                        if (kcol > q0 + 16 + quad * 4 + r) s1[t][r] = -1e30f;
                    }
            }
#pragma unroll
            for (int t = 0; t < 4; t++)
#pragma unroll
                for (int r = 0; r < 4; r++) {
                    float p0 = __expf(s0[t][r]);
                    ls0[r] += p0;
                    plds[w][0][quad * 4 + r][t * 16 + lane15] = f2bf(p0);
                    float p1 = __expf(s1[t][r]);
                    ls1[r] += p1;
                    plds[w][1][quad * 4 + r][t * 16 + lane15] = f2bf(p1);
                }
            WAIT_LGKM0();                         // wave-local plds RAW
#pragma unroll
            for (int c2 = 0; c2 < 2; c2++) {
                s16x8 pf0 = *(const s16x8*)(&plds[w][0][lane15][c2 * 32 + quad * 8]);
                s16x8 pf1 = *(const s16x8*)(&plds[w][1][lane15][c2 * 32 + quad * 8]);
#pragma unroll
                for (int t = 0; t < 4; t++) {
                    s16x8 vf = *(const s16x8*)(Vb + (2 * t + c2) * 512 + l * 8);
                    o0[t] = mfma16(pf0, vf, o0[t]);
                    o1[t] = mfma16(pf1, vf, o1[t]);
                }
            }
            // consumer lgkm reads drain at next barrier before buf reuse
        }
        buf ^= 1;
    }

    if (w < 4) {
#pragma unroll
        for (int r = 0; r < 4; r++) {
#pragma unroll
            for (int d = 1; d < 16; d <<= 1) {
                ls0[r] += __shfl_xor(ls0[r], d, 64);
                ls1[r] += __shfl_xor(ls1[r], d, 64);
            }
        }

        size_t slot = (size_t)b * 80 + g;
        float* ob = op + slot * 8192;             // 128 rows x 64 cols
#pragma unroll
        for (int t = 0; t < 4; t++)
#pragma unroll
            for (int r = 0; r < 4; r++) {
                ob[(w * 32 + quad * 4 + r) * 64 + t * 16 + lane15]      = o0[t][r];
                ob[(w * 32 + 16 + quad * 4 + r) * 64 + t * 16 + lane15] = o1[t][r];
            }
        if (lane15 == 0) {
#pragma unroll
            for (int r = 0; r < 4; r++) {
                lp[slot * 128 + w * 32 + quad * 4 + r]      = ls0[r];
                lp[slot * 128 + w * 32 + 16 + quad * 4 + r] = ls1[r];
            }
        }
    }
}

// ---------------------------------------------------------------------------
// Kernel 4: combine attention partials: out = (sum_c o_c) / (sum_c l_c).
// n <= 4 partials per row.
// ---------------------------------------------------------------------------
__global__ __launch_bounds__(256) void attn_combine(const float* __restrict__ op,
                                                    const float* __restrict__ lp,
                                                    float* __restrict__ out) {
    int e = blockIdx.x * 256 + threadIdx.x;       // 0 .. 262143
    int c4 = (e & 15) * 4;
    int row = e >> 4;                             // global row
    int b   = row >> 12;
    int tr  = row & (SEQ - 1);
    int Q   = tr >> 7;                            // 128-row q-block
    int r128 = tr & 127;
    int a   = Q >> 3;
    int bq  = Q & 7;
    int n   = a + 1;
    int g0  = (a + 1) * (4 * a + bq);
    f32x4 os = {0.f, 0.f, 0.f, 0.f};
    float ls = 0.f;
    for (int c = 0; c < n; c++) {
        size_t slot = (size_t)b * 80 + g0 + c;
        os += *(const f32x4*)(op + slot * 8192 + r128 * 64 + c4);
        ls += lp[slot * 128 + r128];
    }
    f32x4 r = os / ls;
    *(f32x4*)(out + (size_t)row * HS + c4) = r;
}

// ---------------------------------------------------------------------------
extern "C" void kernel_launch(void* const* d_in, const int* in_sizes, int n_in,
                              void* d_out, int out_size, void* d_ws, size_t ws_size,
                              hipStream_t stream) {
    const float* x  = (const float*)d_in[0];
    const float* Wq = (const float*)d_in[1];
    const float* Wk = (const float*)d_in[2];
    const float* Wv = (const float*)d_in[3];
    float* out = (float*)d_out;

    unsigned short* ws   = (unsigned short*)d_ws;
    unsigned short* wp   = ws;                    // 384 KB (pad to 512 KB)
    unsigned short* qws  = ws + 262144;           // 2 MB
    unsigned short* kws  = ws + 1310720;          // 2 MB
    unsigned short* vtws = ws + 2359296;          // 2 MB (V transposed [B,64,SEQ])
    float* op = (float*)(ws + 3407872);           // 320 x 8192 fp32 = 10.5 MB
    float* lp = op + 2621440;                     // 320 x 128 fp32

    hipLaunchKernelGGL(pack_w,      dim3(96),   dim3(256), 0, stream, Wq, Wk, Wv, wp);
    hipLaunchKernelGGL(proj,        dim3(512),  dim3(256), 0, stream, x, wp, qws, kws, vtws);
    hipLaunchKernelGGL(attn_part,   dim3(320),  dim3(320), 0, stream, qws, kws, vtws, op, lp);
    hipLaunchKernelGGL(attn_combine,dim3(1024), dim3(256), 0, stream, op, lp, out);
}

// Round 3
// 152.451 us; speedup vs baseline: 1.0441x; 1.0441x over previous
//
#include <hip/hip_runtime.h>
#include <hip/hip_bf16.h>

#define EMB   1024
#define HS    64
#define BATCH 4
#define SEQ   4096
#define MTOT  (BATCH*SEQ)   // 16384

#define WAIT_LGKM0() asm volatile("s_waitcnt lgkmcnt(0)" ::: "memory")

typedef float  f32x4 __attribute__((ext_vector_type(4)));
typedef short  s16x8 __attribute__((ext_vector_type(8)));
typedef __bf16 bf16x8 __attribute__((ext_vector_type(8)));

__device__ __forceinline__ unsigned short f2bf(float f) {
    unsigned int u = __float_as_uint(f);
    u = (u + 0x7fffu + ((u >> 16) & 1u)) >> 16;   // RNE
    return (unsigned short)u;
}
__device__ __forceinline__ unsigned int pkbf(float lo, float hi) {
#if __has_builtin(__builtin_amdgcn_cvt_pk_bf16_f32)
    return __builtin_bit_cast(unsigned int,
        __builtin_amdgcn_cvt_pk_bf16_f32(lo, hi));
#else
    return (unsigned int)f2bf(lo) | ((unsigned int)f2bf(hi) << 16);
#endif
}
__device__ __forceinline__ s16x8 cvt8(float4 a, float4 b) {
    union { unsigned int u[4]; s16x8 v; } r;
    r.u[0] = pkbf(a.x, a.y); r.u[1] = pkbf(a.z, a.w);
    r.u[2] = pkbf(b.x, b.y); r.u[3] = pkbf(b.z, b.w);
    return r.v;
}
__device__ __forceinline__ f32x4 mfma16(s16x8 a, s16x8 b, f32x4 c) {
    return __builtin_amdgcn_mfma_f32_16x16x32_bf16(
        __builtin_bit_cast(bf16x8, a), __builtin_bit_cast(bf16x8, b), c, 0, 0, 0);
}
// async global->LDS, 16B/lane; lds dest = uniform base + lane*16
__device__ __forceinline__ void ld_lds16(const void* g, unsigned short* l) {
    __builtin_amdgcn_global_load_lds(
        (const __attribute__((address_space(1))) unsigned int*)g,
        (__attribute__((address_space(3))) unsigned int*)l, 16, 0, 0);
}

// ---------------------------------------------------------------------------
// Kernel 1: pack W (fp32 [1024,64] x3) into MFMA-B-fragment order, bf16.
// t 0-3 -> Wq (pre-scaled by 1/32 == emb^-0.5, exact), 4-7 -> Wk, 8-11 -> Wv
// ---------------------------------------------------------------------------
__global__ __launch_bounds__(256) void pack_w(const float* __restrict__ Wq,
                                              const float* __restrict__ Wk,
                                              const float* __restrict__ Wv,
                                              unsigned short* __restrict__ wp) {
    int idx = blockIdx.x * 256 + threadIdx.x;     // 0 .. 24575
    int l = idx & 63;
    int s = (idx >> 6) & 31;
    int t = idx >> 11;                            // 0..11
    const float* W = (t < 4) ? Wq : (t < 8) ? Wk : Wv;
    float scale = (t < 4) ? 0.03125f : 1.0f;
    int n  = ((t & 3) * 16) + (l & 15);
    int k0 = s * 32 + ((l >> 4) * 8);
    s16x8 v;
#pragma unroll
    for (int j = 0; j < 8; j++)
        v[j] = (short)f2bf(W[(size_t)(k0 + j) * HS + n] * scale);
    *(s16x8*)(wp + (size_t)idx * 8) = v;
}

// ---------------------------------------------------------------------------
// Kernel 2 (R8 proven): fused QKV projection, BK=64 double-steps.
// Block = 32 rows x 192 cols, 512 blocks (2/CU).
// ---------------------------------------------------------------------------
__global__ __launch_bounds__(256) void proj(const float* __restrict__ x,
                                            const unsigned short* __restrict__ wp,
                                            unsigned short* __restrict__ qws,
                                            unsigned short* __restrict__ kws,
                                            unsigned short* __restrict__ vtws) {
    __shared__ unsigned short xb[2][2][2048];     // [buf][sub] 4 KB each
    __shared__ unsigned short wb2[2][12288];      // [buf] 24 KB each
    __shared__ unsigned short vt[32][72];         // V transpose staging
    int l = threadIdx.x & 63, w = threadIdx.x >> 6;
    int lane15 = l & 15, quad = l >> 4;
    int rh = w & 1, ts = w >> 1;
    int row0 = blockIdx.x * 32;

    auto stage = [&](int buf, int sg2) {
        int d = w * 64 + l;
        int row = d >> 3, cs = d & 7;
        int sc = cs ^ (row & 7);                  // XOR swizzle (bank spread)
#pragma unroll
        for (int sp = 0; sp < 2; sp++)
            ld_lds16(x + (size_t)(row0 + row) * EMB + sg2 * 64 + sp * 32 + sc * 4,
                     &xb[buf][sp][w * 512]);
#pragma unroll
        for (int j = 0; j < 6; j++) {
            int f = w + 4 * j;
            int sp = f / 12, t = f % 12;
            ld_lds16(wp + ((size_t)(t * 32 + sg2 * 2 + sp) * 64 + l) * 8,
                     &wb2[buf][f * 512]);
        }
    };

    int xrow = rh * 16 + lane15;
    int rsw = xrow & 7;
    f32x4 acc[6] = {};

    stage(0, 0);
    int buf = 0;
    for (int sg2 = 0; sg2 < 16; sg2++) {
        __syncthreads();
        if (sg2 < 15) stage(buf ^ 1, sg2 + 1);
#pragma unroll
        for (int sp = 0; sp < 2; sp++) {
            float4 lo = *(const float4*)&xb[buf][sp][(xrow * 8 + ((2 * quad)     ^ rsw)) * 8];
            float4 hi = *(const float4*)&xb[buf][sp][(xrow * 8 + ((2 * quad + 1) ^ rsw)) * 8];
            s16x8 af = cvt8(lo, hi);
#pragma unroll
            for (int j = 0; j < 6; j++) {
                int t = ts + 2 * j;
                s16x8 bfr = *(const s16x8*)&wb2[buf][(sp * 12 + t) * 512 + l * 8];
                acc[j] = mfma16(af, bfr, acc[j]);
            }
        }
        buf ^= 1;
    }

#pragma unroll
    for (int r = 0; r < 4; r++) {
        int row = row0 + rh * 16 + quad * 4 + r;
#pragma unroll
        for (int j = 0; j < 2; j++) {
            int tq = ts + 2 * j;
            qws[(size_t)row * HS + tq * 16 + lane15] = f2bf(acc[j][r]);
            kws[(size_t)row * HS + tq * 16 + lane15] = f2bf(acc[j + 2][r]);
            vt[rh * 16 + quad * 4 + r][tq * 16 + lane15] = f2bf(acc[j + 4][r]);
        }
    }
    __syncthreads();
    if (threadIdx.x < 128) {
        int h = threadIdx.x & 63, half = threadIdx.x >> 6;
        int b = row0 >> 12, tp0 = row0 & (SEQ - 1);
        unsigned short tmp[16];
#pragma unroll
        for (int j = 0; j < 16; j++) tmp[j] = vt[half * 16 + j][h];
        unsigned short* dst = vtws + ((size_t)b * HS + h) * SEQ + tp0 + half * 16;
        *(s16x8*)dst       = *(s16x8*)tmp;
        *(s16x8*)(dst + 8) = *(s16x8*)(tmp + 8);
    }
}

// ---------------------------------------------------------------------------
// Kernel 3: flash attention, 128-row q-block (2 16-row frags / wave),
// chunk = 8 k-tiles (was 16 — R2's 320-block grid was latency-bound at
// 6.8% occupancy). 576 blocks -> 2.25 blocks/CU resident (LDS 50 KB
// allows 3/CU), ~11 waves/CU.
// Sync: barrier DOUBLE-BUFFER (m97 pattern) — producer wave (w==4) issues
// global_load_lds for tile s+1; its __syncthreads arrival carries the
// implicit vmcnt(0) drain, consumers' arrival drains their lgkm reads.
// Work decode: per batch, q-blocks Q=0..31 grouped by a=Q>>2 (n=a+1
// chunks each); group a starts at slot 2a(a+1), Q=4a+oQ.
// ---------------------------------------------------------------------------
__global__ __launch_bounds__(320) void attn_part(const unsigned short* __restrict__ qws,
                                                 const unsigned short* __restrict__ kws,
                                                 const unsigned short* __restrict__ vtws,
                                                 float* __restrict__ op,
                                                 float* __restrict__ lp) {
    __shared__ unsigned short ldsKV[2][2][4096];  // [buf][K|V] 8 KB each = 32 KB
    __shared__ unsigned short plds[4][2][16][72]; // [wave][frag] 18 KB

    int l = threadIdx.x & 63;
    int w = threadIdx.x >> 6;                     // 0..4
    int lane15 = l & 15, quad = l >> 4;

    int W = blockIdx.x;                           // 0..575
    int b = W / 144;
    int g = W - b * 144;
    int a = 0;
    while (g >= 2 * (a + 1) * (a + 2)) a++;       // a in [0,7]
    int off = g - 2 * a * (a + 1);
    int oQ  = off / (a + 1);
    int c   = off - oQ * (a + 1);
    int Q   = 4 * a + oQ;                         // 128-row q-block, 0..31
    int lenT = 2 * (Q + 1);                       // k-tiles covered by q-block
    int t0 = c * 8;
    int steps = min(8, lenT - t0);                // 2..8, uniform in block
    int diagT = 2 * Q;                            // tiles >= diagT need masking

    auto stage = [&](int buf, int kt) {
        int c0 = kt * 64;
#pragma unroll
        for (int s2 = 0; s2 < 8; s2++) {          // K slots
            int t = s2 >> 1, h = s2 & 1;
            ld_lds16(kws + ((size_t)b * SEQ + c0 + t * 16 + lane15) * HS
                         + h * 32 + quad * 8,
                     &ldsKV[buf][0][s2 * 512]);
        }
#pragma unroll
        for (int s2 = 0; s2 < 8; s2++) {          // V slots
            int t = s2 >> 1, h = s2 & 1;
            ld_lds16(vtws + ((size_t)b * HS + t * 16 + lane15) * SEQ
                          + c0 + h * 32 + quad * 8,
                     &ldsKV[buf][1][s2 * 512]);
        }
    };

    int q0 = Q * 128 + (w & 3) * 32;              // consumer's first q-row
    s16x8 qf00 = {}, qf01 = {}, qf10 = {}, qf11 = {};
    f32x4 o0[4] = {}, o1[4] = {};
    float ls0[4] = {0.f, 0.f, 0.f, 0.f};
    float ls1[4] = {0.f, 0.f, 0.f, 0.f};

    if (w == 4) {
        stage(0, t0);                             // prologue: tile 0 -> buf 0
    } else {
        const unsigned short* qb0 =
            qws + ((size_t)b * SEQ + q0 + lane15) * HS + quad * 8;
        const unsigned short* qb1 = qb0 + 16 * HS;
        qf00 = *(const s16x8*)(qb0);
        qf01 = *(const s16x8*)(qb0 + 32);
        qf10 = *(const s16x8*)(qb1);
        qf11 = *(const s16x8*)(qb1 + 32);
    }

    int buf = 0;
    for (int s = 0; s < steps; s++) {
        __syncthreads();                          // tile s landed; buf^1 free
        if (w == 4) {
            if (s + 1 < steps) stage(buf ^ 1, t0 + s + 1);
        } else {
            int kt = t0 + s;
            const unsigned short* Kb = ldsKV[buf][0];
            const unsigned short* Vb = ldsKV[buf][1];

            f32x4 s0[4] = {}, s1[4] = {};
#pragma unroll
            for (int t = 0; t < 4; t++) {
                s16x8 kf0 = *(const s16x8*)(Kb + (2 * t) * 512 + l * 8);
                s16x8 kf1 = *(const s16x8*)(Kb + (2 * t + 1) * 512 + l * 8);
                s0[t] = mfma16(qf00, kf0, s0[t]);
                s0[t] = mfma16(qf01, kf1, s0[t]);
                s1[t] = mfma16(qf10, kf0, s1[t]);
                s1[t] = mfma16(qf11, kf1, s1[t]);
            }
            if (kt >= diagT) {
                int c0 = kt * 64;
#pragma unroll
                for (int t = 0; t < 4; t++)
#pragma unroll
                    for (int r = 0; r < 4; r++) {
                        int kcol = c0 + t * 16 + lane15;
                        if (kcol > q0 + quad * 4 + r)      s0[t][r] = -1e30f;
                        if (kcol > q0 + 16 + quad * 4 + r) s1[t][r] = -1e30f;
                    }
            }
#pragma unroll
            for (int t = 0; t < 4; t++)
#pragma unroll
                for (int r = 0; r < 4; r++) {
                    float p0 = __expf(s0[t][r]);
                    ls0[r] += p0;
                    plds[w][0][quad * 4 + r][t * 16 + lane15] = f2bf(p0);
                    float p1 = __expf(s1[t][r]);
                    ls1[r] += p1;
                    plds[w][1][quad * 4 + r][t * 16 + lane15] = f2bf(p1);
                }
            WAIT_LGKM0();                         // wave-local plds RAW
#pragma unroll
            for (int c2 = 0; c2 < 2; c2++) {
                s16x8 pf0 = *(const s16x8*)(&plds[w][0][lane15][c2 * 32 + quad * 8]);
                s16x8 pf1 = *(const s16x8*)(&plds[w][1][lane15][c2 * 32 + quad * 8]);
#pragma unroll
                for (int t = 0; t < 4; t++) {
                    s16x8 vf = *(const s16x8*)(Vb + (2 * t + c2) * 512 + l * 8);
                    o0[t] = mfma16(pf0, vf, o0[t]);
                    o1[t] = mfma16(pf1, vf, o1[t]);
                }
            }
            // consumer lgkm reads drain at next barrier before buf reuse
        }
        buf ^= 1;
    }

    if (w < 4) {
#pragma unroll
        for (int r = 0; r < 4; r++) {
#pragma unroll
            for (int d = 1; d < 16; d <<= 1) {
                ls0[r] += __shfl_xor(ls0[r], d, 64);
                ls1[r] += __shfl_xor(ls1[r], d, 64);
            }
        }

        size_t slot = (size_t)b * 144 + g;
        float* ob = op + slot * 8192;             // 128 rows x 64 cols
#pragma unroll
        for (int t = 0; t < 4; t++)
#pragma unroll
            for (int r = 0; r < 4; r++) {
                ob[(w * 32 + quad * 4 + r) * 64 + t * 16 + lane15]      = o0[t][r];
                ob[(w * 32 + 16 + quad * 4 + r) * 64 + t * 16 + lane15] = o1[t][r];
            }
        if (lane15 == 0) {
#pragma unroll
            for (int r = 0; r < 4; r++) {
                lp[slot * 128 + w * 32 + quad * 4 + r]      = ls0[r];
                lp[slot * 128 + w * 32 + 16 + quad * 4 + r] = ls1[r];
            }
        }
    }
}

// ---------------------------------------------------------------------------
// Kernel 4: combine attention partials: out = (sum_c o_c) / (sum_c l_c).
// n <= 8 partials per row.
// ---------------------------------------------------------------------------
__global__ __launch_bounds__(256) void attn_combine(const float* __restrict__ op,
                                                    const float* __restrict__ lp,
                                                    float* __restrict__ out) {
    int e = blockIdx.x * 256 + threadIdx.x;       // 0 .. 262143
    int c4 = (e & 15) * 4;
    int row = e >> 4;                             // global row
    int b   = row >> 12;
    int tr  = row & (SEQ - 1);
    int Q   = tr >> 7;                            // 128-row q-block
    int r128 = tr & 127;
    int a   = Q >> 2;
    int bq  = Q & 3;
    int n   = a + 1;
    int g0  = (a + 1) * (2 * a + bq);             // 2a(a+1) + bq*(a+1)
    f32x4 os = {0.f, 0.f, 0.f, 0.f};
    float ls = 0.f;
    for (int c = 0; c < n; c++) {
        size_t slot = (size_t)b * 144 + g0 + c;
        os += *(const f32x4*)(op + slot * 8192 + r128 * 64 + c4);
        ls += lp[slot * 128 + r128];
    }
    f32x4 r = os / ls;
    *(f32x4*)(out + (size_t)row * HS + c4) = r;
}

// ---------------------------------------------------------------------------
extern "C" void kernel_launch(void* const* d_in, const int* in_sizes, int n_in,
                              void* d_out, int out_size, void* d_ws, size_t ws_size,
                              hipStream_t stream) {
    const float* x  = (const float*)d_in[0];
    const float* Wq = (const float*)d_in[1];
    const float* Wk = (const float*)d_in[2];
    const float* Wv = (const float*)d_in[3];
    float* out = (float*)d_out;

    unsigned short* ws   = (unsigned short*)d_ws;
    unsigned short* wp   = ws;                    // 384 KB (pad to 512 KB)
    unsigned short* qws  = ws + 262144;           // 2 MB
    unsigned short* kws  = ws + 1310720;          // 2 MB
    unsigned short* vtws = ws + 2359296;          // 2 MB (V transposed [B,64,SEQ])
    float* op = (float*)(ws + 3407872);           // 576 x 8192 fp32 = 18.9 MB
    float* lp = op + 4718592;                     // 576 x 128 fp32

    hipLaunchKernelGGL(pack_w,      dim3(96),   dim3(256), 0, stream, Wq, Wk, Wv, wp);
    hipLaunchKernelGGL(proj,        dim3(512),  dim3(256), 0, stream, x, wp, qws, kws, vtws);
    hipLaunchKernelGGL(attn_part,   dim3(576),  dim3(320), 0, stream, qws, kws, vtws, op, lp);
    hipLaunchKernelGGL(attn_combine,dim3(1024), dim3(256), 0, stream, op, lp, out);
}